// Round 9
// baseline (643.182 us; speedup 1.0000x reference)
//
#include <hip/hip_runtime.h>

// ---------------------------------------------------------------------------
// HybridSAGEClassifier: 3x SAGEConv(mean) + BN + ReLU, then fusion MLP.
// R1: project-first (mean(x[src])@Wl == mean((x@Wl)[src])).
// R2: scatter-atomics -> CSR + register gather.
// R3: single-block scan -> 3-stage parallel scan.
// R4: register-blocked GEMM + norm/ReLU fused into consumers.
// R5: one-pass ELL; bf16 gather table.
// R6: MFMA 16x16x32_bf16, bf16x3 split (~fp32 accuracy).
// R7: gather: 4-node interleaved chains, 8-edge uint4 requests; Yr bf16.
// R8: ell_fill -> 16 temporally-sharded dst ranges (L2-resident writes).
// R9: gather was concurrency-starved (26% occ x ~8 reqs/wave; VALU 20%,
//     HBM 14%) -> block-centric: ELL staged in LDS, each lane owns 16 cols
//     of one node and pipelines its own 4-edge-unrolled gather loop (8
//     uint4s in flight, no shuffles); BN stats via LDS atomics; T in bf16
//     (halves T write + consumer reads).
// ---------------------------------------------------------------------------

typedef __attribute__((ext_vector_type(8))) short bf16x8;
typedef __attribute__((ext_vector_type(4))) float f32x4;

__device__ __forceinline__ ushort f2bf(float f) {
  unsigned u = __float_as_uint(f);
  return (ushort)((u + 0x7fff + ((u >> 16) & 1)) >> 16);  // RNE
}
__device__ __forceinline__ float bf2f(ushort h) {
  return __uint_as_float((unsigned)h << 16);
}
__device__ __forceinline__ void unpack8(uint4 v, float* f) {
  f[0] = __uint_as_float(v.x << 16);
  f[1] = __uint_as_float(v.x & 0xffff0000u);
  f[2] = __uint_as_float(v.y << 16);
  f[3] = __uint_as_float(v.y & 0xffff0000u);
  f[4] = __uint_as_float(v.z << 16);
  f[5] = __uint_as_float(v.z & 0xffff0000u);
  f[6] = __uint_as_float(v.w << 16);
  f[7] = __uint_as_float(v.w & 0xffff0000u);
}

// ---- ELL build: temporally sharded scatter (R8) ----------------------------

__global__ __launch_bounds__(256) void ell_fill_sharded(
    const int* __restrict__ ei, int* __restrict__ deg, int* __restrict__ ell,
    int E, int n, int bps) {
  const int shard = blockIdx.x / bps;      // 0..15
  const int bib = blockIdx.x % bps;        // block-in-shard
  const int chunk = n >> 4;                // n/16
  const int lo = shard * chunk;
  const int hi = (shard == 15) ? n : lo + chunk;
  for (int e = bib * 256 + threadIdx.x; e < E; e += bps * 256) {
    int d = ei[E + e];
    if (d >= lo && d < hi) {
      int s = ei[e];
      int pos = atomicAdd(&deg[d], 1);
      if (pos < 64) ell[(size_t)d * 64 + pos] = s;
    }
  }
}

// ---- W prep: combined (Wl|Wr) -> col-major bf16 hi/lo ----------------------

__global__ void prep_w(const float* __restrict__ Wl,
                       const float* __restrict__ Wr, ushort* __restrict__ Whi,
                       ushort* __restrict__ Wlo, int din) {
  int i = blockIdx.x * blockDim.x + threadIdx.x;
  if (i >= 128 * din) return;
  int col = i / din, k = i % din;
  float v = (col < 64) ? Wl[(size_t)k * 64 + col]
                       : Wr[(size_t)k * 64 + (col - 64)];
  ushort h = f2bf(v);
  Whi[i] = h;
  Wlo[i] = f2bf(v - bf2f(h));
}

// ---- MFMA dual GEMM --------------------------------------------------------
// [Ybf | Yrbf] = f(X) @ [Wl | Wr]; f = BN-affine+ReLU (NORM) or identity.
// X is fp32 (XBF16=false) or bf16 (XBF16=true, the T buffer).
template <int DIN, bool NORM, bool XBF16>
__global__ __launch_bounds__(256) void gemm_mfma(
    const void* __restrict__ Xv, const float* __restrict__ ss,
    const ushort* __restrict__ Whi, const ushort* __restrict__ Wlo,
    ushort* __restrict__ Ybf, ushort* __restrict__ Yrbf, int n) {
  constexpr int XS = DIN + 4;
  constexpr int WS = 40;
  __shared__ float sX[64 * XS];
  __shared__ ushort sW[2 * 128 * WS];
  const int tid = threadIdx.x;
  const int w = tid >> 6;
  const int lane = tid & 63;
  const int m = lane & 15;
  const int quad = lane >> 4;
  const int row0 = blockIdx.x * 64;

  if (XBF16) {
    const ushort* X = (const ushort*)Xv;
    for (int i = tid; i < 64 * DIN / 8; i += 256) {
      int r = (i * 8) / DIN;
      int k = (i * 8) % DIN;
      int row = min(row0 + r, n - 1);
      uint4 v = *reinterpret_cast<const uint4*>(X + (size_t)row * DIN + k);
      float f[8];
      unpack8(v, f);
      if (NORM) {
#pragma unroll
        for (int j = 0; j < 8; j++)
          f[j] = fmaxf(fmaf(f[j], ss[k + j], ss[64 + k + j]), 0.f);
      }
      *reinterpret_cast<float4*>(sX + r * XS + k) =
          make_float4(f[0], f[1], f[2], f[3]);
      *reinterpret_cast<float4*>(sX + r * XS + k + 4) =
          make_float4(f[4], f[5], f[6], f[7]);
    }
  } else {
    const float* X = (const float*)Xv;
    for (int i = tid; i < 64 * DIN / 4; i += 256) {
      int r = (i * 4) / DIN;
      int k = (i * 4) % DIN;
      int row = min(row0 + r, n - 1);
      float4 v = *reinterpret_cast<const float4*>(X + (size_t)row * DIN + k);
      if (NORM) {
        v.x = fmaxf(fmaf(v.x, ss[k + 0], ss[64 + k + 0]), 0.f);
        v.y = fmaxf(fmaf(v.y, ss[k + 1], ss[64 + k + 1]), 0.f);
        v.z = fmaxf(fmaf(v.z, ss[k + 2], ss[64 + k + 2]), 0.f);
        v.w = fmaxf(fmaf(v.w, ss[k + 3], ss[64 + k + 3]), 0.f);
      }
      *reinterpret_cast<float4*>(sX + r * XS + k) = v;
    }
  }

  f32x4 acc[8];
#pragma unroll
  for (int t = 0; t < 8; t++) acc[t] = (f32x4){0.f, 0.f, 0.f, 0.f};

  for (int kc = 0; kc < DIN; kc += 32) {
    __syncthreads();
    for (int i = tid; i < 512; i += 256) {
      int col = i >> 2;
      int k = (i & 3) * 8;
      *reinterpret_cast<uint4*>(sW + col * WS + k) =
          *reinterpret_cast<const uint4*>(Whi + (size_t)col * DIN + kc + k);
      *reinterpret_cast<uint4*>(sW + 128 * WS + col * WS + k) =
          *reinterpret_cast<const uint4*>(Wlo + (size_t)col * DIN + kc + k);
    }
    __syncthreads();
    const float* ap = sX + (w * 16 + m) * XS + kc + quad * 8;
    float4 a0 = *reinterpret_cast<const float4*>(ap);
    float4 a1 = *reinterpret_cast<const float4*>(ap + 4);
    float av[8] = {a0.x, a0.y, a0.z, a0.w, a1.x, a1.y, a1.z, a1.w};
    bf16x8 Ahi, Alo;
#pragma unroll
    for (int j = 0; j < 8; j++) {
      ushort h = f2bf(av[j]);
      Ahi[j] = (short)h;
      Alo[j] = (short)f2bf(av[j] - bf2f(h));
    }
#pragma unroll
    for (int t = 0; t < 8; t++) {
      bf16x8 Bhi =
          *reinterpret_cast<const bf16x8*>(sW + (t * 16 + m) * WS + quad * 8);
      bf16x8 Blo = *reinterpret_cast<const bf16x8*>(sW + 128 * WS +
                                                    (t * 16 + m) * WS +
                                                    quad * 8);
      acc[t] = __builtin_amdgcn_mfma_f32_16x16x32_bf16(Ahi, Bhi, acc[t], 0, 0, 0);
      acc[t] = __builtin_amdgcn_mfma_f32_16x16x32_bf16(Ahi, Blo, acc[t], 0, 0, 0);
      acc[t] = __builtin_amdgcn_mfma_f32_16x16x32_bf16(Alo, Bhi, acc[t], 0, 0, 0);
    }
  }

#pragma unroll
  for (int t = 0; t < 8; t++) {
    int col = t * 16 + m;
#pragma unroll
    for (int r = 0; r < 4; r++) {
      int grow = row0 + w * 16 + quad * 4 + r;
      if (grow < n) {
        ushort v = f2bf(acc[t][r]);
        if (t < 4)
          Ybf[(size_t)grow * 64 + col] = v;
        else
          Yrbf[(size_t)grow * 64 + (col - 64)] = v;
      }
    }
  }
}

// ---- gather v3: block-centric, per-lane edge loop --------------------------
// Block = 32 nodes x 128 threads. ELL rows staged in LDS (only needed
// 16-col chunks). Thread (r=tid>>2, p=tid&3) owns cols p*16..p*16+15 of
// node r and loops that node's edges, 4-edge unrolled -> 8 independent
// uint4 gathers in flight, no cross-lane reduction. BN stats via LDS
// atomics. T written in bf16.
__global__ __launch_bounds__(128) void gather_combine(
    const ushort* __restrict__ Ybf, const ushort* __restrict__ Yrbf,
    const int* __restrict__ ell, const int* __restrict__ deg,
    const float* __restrict__ bias, ushort* __restrict__ Tbf,
    float* __restrict__ stats, int n) {
  __shared__ int sEll[32 * 64];
  __shared__ int sDeg[32];
  __shared__ int sMax;
  __shared__ float sStats[128];
  const int tid = threadIdx.x;
  const int node0 = blockIdx.x * 32;
  const int r = tid >> 2;
  const int p = tid & 3;

  sStats[tid] = 0.f;
  if (tid < 32) {
    int nd = node0 + tid;
    sDeg[tid] = (nd < n) ? min(deg[nd], 64) : 0;
  }
  __syncthreads();
  if (tid == 0) {
    int mx = 0;
    for (int i = 0; i < 32; i++) mx = max(mx, sDeg[i]);
    sMax = mx;
  }
  __syncthreads();
  const int nchunk = (sMax + 15) >> 4;
  for (int c = 0; c < nchunk; c++) {
    if (node0 + r < n)
      *reinterpret_cast<int4*>(&sEll[r * 64 + c * 16 + p * 4]) =
          *reinterpret_cast<const int4*>(
              &ell[(size_t)(node0 + r) * 64 + c * 16 + p * 4]);
  }
  __syncthreads();

  const int myNode = node0 + r;
  const int dg = sDeg[r];
  const int* erow = &sEll[r * 64];
  const int co = p * 16;  // first owned column

  float acc[16];
#pragma unroll
  for (int c = 0; c < 16; c++) acc[c] = 0.f;

  int i = 0;
  for (; i + 4 <= dg; i += 4) {
    int s0 = erow[i + 0], s1 = erow[i + 1], s2 = erow[i + 2], s3 = erow[i + 3];
    const ushort* p0 = Ybf + (size_t)s0 * 64 + co;
    const ushort* p1 = Ybf + (size_t)s1 * 64 + co;
    const ushort* p2 = Ybf + (size_t)s2 * 64 + co;
    const ushort* p3 = Ybf + (size_t)s3 * 64 + co;
    uint4 a0 = *reinterpret_cast<const uint4*>(p0);
    uint4 b0 = *reinterpret_cast<const uint4*>(p0 + 8);
    uint4 a1 = *reinterpret_cast<const uint4*>(p1);
    uint4 b1 = *reinterpret_cast<const uint4*>(p1 + 8);
    uint4 a2 = *reinterpret_cast<const uint4*>(p2);
    uint4 b2 = *reinterpret_cast<const uint4*>(p2 + 8);
    uint4 a3 = *reinterpret_cast<const uint4*>(p3);
    uint4 b3 = *reinterpret_cast<const uint4*>(p3 + 8);
    float f[8];
    unpack8(a0, f);
#pragma unroll
    for (int c = 0; c < 8; c++) acc[c] += f[c];
    unpack8(b0, f);
#pragma unroll
    for (int c = 0; c < 8; c++) acc[8 + c] += f[c];
    unpack8(a1, f);
#pragma unroll
    for (int c = 0; c < 8; c++) acc[c] += f[c];
    unpack8(b1, f);
#pragma unroll
    for (int c = 0; c < 8; c++) acc[8 + c] += f[c];
    unpack8(a2, f);
#pragma unroll
    for (int c = 0; c < 8; c++) acc[c] += f[c];
    unpack8(b2, f);
#pragma unroll
    for (int c = 0; c < 8; c++) acc[8 + c] += f[c];
    unpack8(a3, f);
#pragma unroll
    for (int c = 0; c < 8; c++) acc[c] += f[c];
    unpack8(b3, f);
#pragma unroll
    for (int c = 0; c < 8; c++) acc[8 + c] += f[c];
  }
  for (; i < dg; i++) {
    const ushort* pp = Ybf + (size_t)erow[i] * 64 + co;
    uint4 a = *reinterpret_cast<const uint4*>(pp);
    uint4 b = *reinterpret_cast<const uint4*>(pp + 8);
    float f[8];
    unpack8(a, f);
#pragma unroll
    for (int c = 0; c < 8; c++) acc[c] += f[c];
    unpack8(b, f);
#pragma unroll
    for (int c = 0; c < 8; c++) acc[8 + c] += f[c];
  }

  if (myNode < n) {
    float iv = 1.0f / (float)max(dg, 1);
    const ushort* yp = Yrbf + (size_t)myNode * 64 + co;
    uint4 ya = *reinterpret_cast<const uint4*>(yp);
    uint4 yb = *reinterpret_cast<const uint4*>(yp + 8);
    float yr[16];
    unpack8(ya, yr);
    unpack8(yb, yr + 8);
    float4 bc0 = *reinterpret_cast<const float4*>(bias + co);
    float4 bc1 = *reinterpret_cast<const float4*>(bias + co + 4);
    float4 bc2 = *reinterpret_cast<const float4*>(bias + co + 8);
    float4 bc3 = *reinterpret_cast<const float4*>(bias + co + 12);
    float bcv[16] = {bc0.x, bc0.y, bc0.z, bc0.w, bc1.x, bc1.y, bc1.z, bc1.w,
                     bc2.x, bc2.y, bc2.z, bc2.w, bc3.x, bc3.y, bc3.z, bc3.w};
    float t[16];
#pragma unroll
    for (int c = 0; c < 16; c++) t[c] = fmaf(acc[c], iv, bcv[c] + yr[c]);
    // pack to bf16 and store (32 B)
    uint4 o1, o2;
    o1.x = (uint)f2bf(t[0]) | ((uint)f2bf(t[1]) << 16);
    o1.y = (uint)f2bf(t[2]) | ((uint)f2bf(t[3]) << 16);
    o1.z = (uint)f2bf(t[4]) | ((uint)f2bf(t[5]) << 16);
    o1.w = (uint)f2bf(t[6]) | ((uint)f2bf(t[7]) << 16);
    o2.x = (uint)f2bf(t[8]) | ((uint)f2bf(t[9]) << 16);
    o2.y = (uint)f2bf(t[10]) | ((uint)f2bf(t[11]) << 16);
    o2.z = (uint)f2bf(t[12]) | ((uint)f2bf(t[13]) << 16);
    o2.w = (uint)f2bf(t[14]) | ((uint)f2bf(t[15]) << 16);
    ushort* tp = Tbf + (size_t)myNode * 64 + co;
    *reinterpret_cast<uint4*>(tp) = o1;
    *reinterpret_cast<uint4*>(tp + 8) = o2;
#pragma unroll
    for (int c = 0; c < 16; c++) {
      atomicAdd(&sStats[co + c], t[c]);
      atomicAdd(&sStats[64 + co + c], t[c] * t[c]);
    }
  }
  __syncthreads();
  atomicAdd(&stats[tid], sStats[tid]);
}

// ---- BN finalize: ss[c]=scale, ss[64+c]=shift ------------------------------

__global__ void bn_finalize(const float* __restrict__ stats,
                            const float* __restrict__ g,
                            const float* __restrict__ be,
                            float* __restrict__ ss, int n) {
  int c = threadIdx.x;  // 64 threads
  float invn = 1.0f / (float)n;
  float mu = stats[c] * invn;
  float var = fmaf(-mu, mu, stats[64 + c] * invn);  // biased var
  float sc = g[c] * rsqrtf(var + 1e-5f);
  ss[c] = sc;
  ss[64 + c] = fmaf(-mu, sc, be[c]);
}

// ---- fusion MLP with layer-3 norm+ReLU fused in (T in bf16) ----------------

__global__ __launch_bounds__(256) void fusion_fused(
    const ushort* __restrict__ Tbf, const float* __restrict__ ss,
    const float* __restrict__ xgb, const float* __restrict__ Wf1,
    const float* __restrict__ bf1, const float* __restrict__ Wf2,
    const float* __restrict__ bf2, float* __restrict__ out, int n) {
  __shared__ float sH[64 * 64];
  __shared__ float sW1[65 * 64];
  __shared__ float sW2[64];
  const int tid = threadIdx.x;
  const int c = tid & 63;
  const int w = tid >> 6;
  const int row0 = blockIdx.x * 64;
  for (int i = tid; i < 65 * 64; i += 256) sW1[i] = Wf1[i];
  if (tid < 64) sW2[tid] = Wf2[tid];
  for (int i = tid; i < 512; i += 256) {
    int r = i >> 3;
    int k = (i & 7) * 8;
    int row = min(row0 + r, n - 1);
    uint4 v = *reinterpret_cast<const uint4*>(Tbf + (size_t)row * 64 + k);
    float f[8];
    unpack8(v, f);
#pragma unroll
    for (int j = 0; j < 8; j++)
      f[j] = fmaxf(fmaf(f[j], ss[k + j], ss[64 + k + j]), 0.f);
    *reinterpret_cast<float4*>(sH + r * 64 + k) =
        make_float4(f[0], f[1], f[2], f[3]);
    *reinterpret_cast<float4*>(sH + r * 64 + k + 4) =
        make_float4(f[4], f[5], f[6], f[7]);
  }
  __syncthreads();
  const float b1v = bf1[c];
  const float wx = sW1[64 * 64 + c];
  const float w2v = sW2[c];
  const float b2v = bf2[0];
  float acc[16];
#pragma unroll
  for (int r = 0; r < 16; r++) acc[r] = b1v;
  for (int kk = 0; kk < 64; kk += 4) {
    float4 hv[16];
#pragma unroll
    for (int r = 0; r < 16; r++)
      hv[r] = *reinterpret_cast<const float4*>(sH + (w * 16 + r) * 64 + kk);
    float w0 = sW1[(kk + 0) * 64 + c];
    float w1 = sW1[(kk + 1) * 64 + c];
    float w2 = sW1[(kk + 2) * 64 + c];
    float w3 = sW1[(kk + 3) * 64 + c];
#pragma unroll
    for (int r = 0; r < 16; r++) {
      acc[r] = fmaf(hv[r].x, w0, acc[r]);
      acc[r] = fmaf(hv[r].y, w1, acc[r]);
      acc[r] = fmaf(hv[r].z, w2, acc[r]);
      acc[r] = fmaf(hv[r].w, w3, acc[r]);
    }
  }
#pragma unroll
  for (int r = 0; r < 16; r++) {
    int row = row0 + w * 16 + r;
    float xv = (row < n) ? xgb[row] : 0.f;
    float z = fmaxf(fmaf(xv, wx, acc[r]), 0.f) * w2v;
#pragma unroll
    for (int off = 32; off > 0; off >>= 1) z += __shfl_xor(z, off, 64);
    if (row < n && c == 0) out[row] = z + b2v;
  }
}

// ---- launch ----------------------------------------------------------------

extern "C" void kernel_launch(void* const* d_in, const int* in_sizes, int n_in,
                              void* d_out, int out_size, void* d_ws,
                              size_t ws_size, hipStream_t stream) {
  const float* x = (const float*)d_in[0];
  const int* ei = (const int*)d_in[1];
  const float* xgb = (const float*)d_in[2];
  const float* W1l = (const float*)d_in[3];
  const float* b1 = (const float*)d_in[4];
  const float* W1r = (const float*)d_in[5];
  const float* g1 = (const float*)d_in[6];
  const float* be1 = (const float*)d_in[7];
  const float* W2l = (const float*)d_in[8];
  const float* b2 = (const float*)d_in[9];
  const float* W2r = (const float*)d_in[10];
  const float* g2 = (const float*)d_in[11];
  const float* be2 = (const float*)d_in[12];
  const float* W3l = (const float*)d_in[13];
  const float* b3 = (const float*)d_in[14];
  const float* W3r = (const float*)d_in[15];
  const float* g3 = (const float*)d_in[16];
  const float* be3 = (const float*)d_in[17];
  const float* Wf1 = (const float*)d_in[18];
  const float* bf1 = (const float*)d_in[19];
  const float* Wf2 = (const float*)d_in[20];
  const float* bf2 = (const float*)d_in[21];
  float* out = (float*)d_out;

  const int n = in_sizes[2];      // 100000
  const int E = in_sizes[1] / 2;  // 1200000

  char* w = (char*)d_ws;
  auto alloc = [&](size_t bytes) {
    void* p = (void*)w;
    w += (bytes + 255) & ~(size_t)255;
    return p;
  };
  int* deg = (int*)alloc((size_t)n * 4);
  int* ell = (int*)alloc((size_t)n * 64 * 4);
  ushort* Ybf = (ushort*)alloc((size_t)n * 64 * 2);
  ushort* Yrbf = (ushort*)alloc((size_t)n * 64 * 2);
  ushort* Tbf = (ushort*)alloc((size_t)n * 64 * 2);
  ushort* Whi1 = (ushort*)alloc(128 * 128 * 2);
  ushort* Wlo1 = (ushort*)alloc(128 * 128 * 2);
  ushort* Whi2 = (ushort*)alloc(128 * 64 * 2);
  ushort* Wlo2 = (ushort*)alloc(128 * 64 * 2);
  ushort* Whi3 = (ushort*)alloc(128 * 64 * 2);
  ushort* Wlo3 = (ushort*)alloc(128 * 64 * 2);
  float* stats = (float*)alloc(3 * 128 * 4);
  float* ss = (float*)alloc(3 * 128 * 4);

  hipMemsetAsync(deg, 0, (size_t)n * 4, stream);
  hipMemsetAsync(stats, 0, 3 * 128 * 4, stream);

  const int bps = 2048;
  ell_fill_sharded<<<16 * bps, 256, 0, stream>>>(ei, deg, ell, E, n, bps);
  prep_w<<<64, 256, 0, stream>>>(W1l, W1r, Whi1, Wlo1, 128);
  prep_w<<<32, 256, 0, stream>>>(W2l, W2r, Whi2, Wlo2, 64);
  prep_w<<<32, 256, 0, stream>>>(W3l, W3r, Whi3, Wlo3, 64);

  const int gTile = (n + 63) / 64;
  const int gGath = (n + 31) / 32;

  // ---- layer 1
  gemm_mfma<128, false, false><<<gTile, 256, 0, stream>>>(x, nullptr, Whi1,
                                                          Wlo1, Ybf, Yrbf, n);
  gather_combine<<<gGath, 128, 0, stream>>>(Ybf, Yrbf, ell, deg, b1, Tbf,
                                            stats + 0, n);
  bn_finalize<<<1, 64, 0, stream>>>(stats + 0, g1, be1, ss + 0, n);

  // ---- layer 2 (norm of T1 fused into GEMM staging)
  gemm_mfma<64, true, true><<<gTile, 256, 0, stream>>>(Tbf, ss + 0, Whi2, Wlo2,
                                                       Ybf, Yrbf, n);
  gather_combine<<<gGath, 128, 0, stream>>>(Ybf, Yrbf, ell, deg, b2, Tbf,
                                            stats + 128, n);
  bn_finalize<<<1, 64, 0, stream>>>(stats + 128, g2, be2, ss + 128, n);

  // ---- layer 3
  gemm_mfma<64, true, true><<<gTile, 256, 0, stream>>>(Tbf, ss + 128, Whi3,
                                                       Wlo3, Ybf, Yrbf, n);
  gather_combine<<<gGath, 128, 0, stream>>>(Ybf, Yrbf, ell, deg, b3, Tbf,
                                            stats + 256, n);
  bn_finalize<<<1, 64, 0, stream>>>(stats + 256, g3, be3, ss + 256, n);

  // ---- fusion MLP (norm of T3 fused in)
  fusion_fused<<<gTile, 256, 0, stream>>>(Tbf, ss + 256, xgb, Wf1, bf1, Wf2,
                                          bf2, out, n);
}

// Round 10
// 557.058 us; speedup vs baseline: 1.1546x; 1.1546x over previous
//
#include <hip/hip_runtime.h>

// ---------------------------------------------------------------------------
// HybridSAGEClassifier: 3x SAGEConv(mean) + BN + ReLU, then fusion MLP.
// R1: project-first (mean(x[src])@Wl == mean((x@Wl)[src])).
// R2: scatter-atomics -> CSR + register gather.
// R3: single-block scan -> 3-stage parallel scan.
// R4: register-blocked GEMM + norm/ReLU fused into consumers.
// R5: one-pass ELL; bf16 gather table.
// R6: MFMA 16x16x32_bf16, bf16x3 split (~fp32 accuracy).
// R7: gather: 4-node interleaved chains, 8-edge uint4 requests; Yr bf16.
// R8: ell_fill -> 16 temporally-sharded dst ranges (L2-resident writes).
// R9 FAILED: block-centric per-lane gather regressed 88->120us (exec-mask
//     trip count = max(deg) over 16 nodes; 322k LDS-atomic conflicts;
//     VALUBusy 20->6%). Lesson: v2's full-row-per-instruction layout with
//     grp-dim independent chains is the right structure for this table.
// R10: revert to R8 gather; keep R9's orthogonal wins (T in bf16 -> halves
//     T write + consumer GEMM staging reads; XBF16 GEMM path).
// ---------------------------------------------------------------------------

typedef __attribute__((ext_vector_type(8))) short bf16x8;
typedef __attribute__((ext_vector_type(4))) float f32x4;

__device__ __forceinline__ ushort f2bf(float f) {
  unsigned u = __float_as_uint(f);
  return (ushort)((u + 0x7fff + ((u >> 16) & 1)) >> 16);  // RNE
}
__device__ __forceinline__ float bf2f(ushort h) {
  return __uint_as_float((unsigned)h << 16);
}
__device__ __forceinline__ void unpack8(uint4 v, float* f) {
  f[0] = __uint_as_float(v.x << 16);
  f[1] = __uint_as_float(v.x & 0xffff0000u);
  f[2] = __uint_as_float(v.y << 16);
  f[3] = __uint_as_float(v.y & 0xffff0000u);
  f[4] = __uint_as_float(v.z << 16);
  f[5] = __uint_as_float(v.z & 0xffff0000u);
  f[6] = __uint_as_float(v.w << 16);
  f[7] = __uint_as_float(v.w & 0xffff0000u);
}

// ---- ELL build: temporally sharded scatter (R8) ----------------------------

__global__ __launch_bounds__(256) void ell_fill_sharded(
    const int* __restrict__ ei, int* __restrict__ deg, int* __restrict__ ell,
    int E, int n, int bps) {
  const int shard = blockIdx.x / bps;      // 0..15
  const int bib = blockIdx.x % bps;        // block-in-shard
  const int chunk = n >> 4;                // n/16
  const int lo = shard * chunk;
  const int hi = (shard == 15) ? n : lo + chunk;
  for (int e = bib * 256 + threadIdx.x; e < E; e += bps * 256) {
    int d = ei[E + e];
    if (d >= lo && d < hi) {
      int s = ei[e];
      int pos = atomicAdd(&deg[d], 1);
      if (pos < 64) ell[(size_t)d * 64 + pos] = s;
    }
  }
}

// ---- W prep: combined (Wl|Wr) -> col-major bf16 hi/lo ----------------------

__global__ void prep_w(const float* __restrict__ Wl,
                       const float* __restrict__ Wr, ushort* __restrict__ Whi,
                       ushort* __restrict__ Wlo, int din) {
  int i = blockIdx.x * blockDim.x + threadIdx.x;
  if (i >= 128 * din) return;
  int col = i / din, k = i % din;
  float v = (col < 64) ? Wl[(size_t)k * 64 + col]
                       : Wr[(size_t)k * 64 + (col - 64)];
  ushort h = f2bf(v);
  Whi[i] = h;
  Wlo[i] = f2bf(v - bf2f(h));
}

// ---- MFMA dual GEMM --------------------------------------------------------
// [Ybf | Yrbf] = f(X) @ [Wl | Wr]; f = BN-affine+ReLU (NORM) or identity.
// X is fp32 (XBF16=false) or bf16 (XBF16=true, the T buffer).
template <int DIN, bool NORM, bool XBF16>
__global__ __launch_bounds__(256) void gemm_mfma(
    const void* __restrict__ Xv, const float* __restrict__ ss,
    const ushort* __restrict__ Whi, const ushort* __restrict__ Wlo,
    ushort* __restrict__ Ybf, ushort* __restrict__ Yrbf, int n) {
  constexpr int XS = DIN + 4;
  constexpr int WS = 40;
  __shared__ float sX[64 * XS];
  __shared__ ushort sW[2 * 128 * WS];
  const int tid = threadIdx.x;
  const int w = tid >> 6;
  const int lane = tid & 63;
  const int m = lane & 15;
  const int quad = lane >> 4;
  const int row0 = blockIdx.x * 64;

  if (XBF16) {
    const ushort* X = (const ushort*)Xv;
    for (int i = tid; i < 64 * DIN / 8; i += 256) {
      int r = (i * 8) / DIN;
      int k = (i * 8) % DIN;
      int row = min(row0 + r, n - 1);
      uint4 v = *reinterpret_cast<const uint4*>(X + (size_t)row * DIN + k);
      float f[8];
      unpack8(v, f);
      if (NORM) {
#pragma unroll
        for (int j = 0; j < 8; j++)
          f[j] = fmaxf(fmaf(f[j], ss[k + j], ss[64 + k + j]), 0.f);
      }
      *reinterpret_cast<float4*>(sX + r * XS + k) =
          make_float4(f[0], f[1], f[2], f[3]);
      *reinterpret_cast<float4*>(sX + r * XS + k + 4) =
          make_float4(f[4], f[5], f[6], f[7]);
    }
  } else {
    const float* X = (const float*)Xv;
    for (int i = tid; i < 64 * DIN / 4; i += 256) {
      int r = (i * 4) / DIN;
      int k = (i * 4) % DIN;
      int row = min(row0 + r, n - 1);
      float4 v = *reinterpret_cast<const float4*>(X + (size_t)row * DIN + k);
      if (NORM) {
        v.x = fmaxf(fmaf(v.x, ss[k + 0], ss[64 + k + 0]), 0.f);
        v.y = fmaxf(fmaf(v.y, ss[k + 1], ss[64 + k + 1]), 0.f);
        v.z = fmaxf(fmaf(v.z, ss[k + 2], ss[64 + k + 2]), 0.f);
        v.w = fmaxf(fmaf(v.w, ss[k + 3], ss[64 + k + 3]), 0.f);
      }
      *reinterpret_cast<float4*>(sX + r * XS + k) = v;
    }
  }

  f32x4 acc[8];
#pragma unroll
  for (int t = 0; t < 8; t++) acc[t] = (f32x4){0.f, 0.f, 0.f, 0.f};

  for (int kc = 0; kc < DIN; kc += 32) {
    __syncthreads();
    for (int i = tid; i < 512; i += 256) {
      int col = i >> 2;
      int k = (i & 3) * 8;
      *reinterpret_cast<uint4*>(sW + col * WS + k) =
          *reinterpret_cast<const uint4*>(Whi + (size_t)col * DIN + kc + k);
      *reinterpret_cast<uint4*>(sW + 128 * WS + col * WS + k) =
          *reinterpret_cast<const uint4*>(Wlo + (size_t)col * DIN + kc + k);
    }
    __syncthreads();
    const float* ap = sX + (w * 16 + m) * XS + kc + quad * 8;
    float4 a0 = *reinterpret_cast<const float4*>(ap);
    float4 a1 = *reinterpret_cast<const float4*>(ap + 4);
    float av[8] = {a0.x, a0.y, a0.z, a0.w, a1.x, a1.y, a1.z, a1.w};
    bf16x8 Ahi, Alo;
#pragma unroll
    for (int j = 0; j < 8; j++) {
      ushort h = f2bf(av[j]);
      Ahi[j] = (short)h;
      Alo[j] = (short)f2bf(av[j] - bf2f(h));
    }
#pragma unroll
    for (int t = 0; t < 8; t++) {
      bf16x8 Bhi =
          *reinterpret_cast<const bf16x8*>(sW + (t * 16 + m) * WS + quad * 8);
      bf16x8 Blo = *reinterpret_cast<const bf16x8*>(sW + 128 * WS +
                                                    (t * 16 + m) * WS +
                                                    quad * 8);
      acc[t] = __builtin_amdgcn_mfma_f32_16x16x32_bf16(Ahi, Bhi, acc[t], 0, 0, 0);
      acc[t] = __builtin_amdgcn_mfma_f32_16x16x32_bf16(Ahi, Blo, acc[t], 0, 0, 0);
      acc[t] = __builtin_amdgcn_mfma_f32_16x16x32_bf16(Alo, Bhi, acc[t], 0, 0, 0);
    }
  }

#pragma unroll
  for (int t = 0; t < 8; t++) {
    int col = t * 16 + m;
#pragma unroll
    for (int r = 0; r < 4; r++) {
      int grow = row0 + w * 16 + quad * 4 + r;
      if (grow < n) {
        ushort v = f2bf(acc[t][r]);
        if (t < 4)
          Ybf[(size_t)grow * 64 + col] = v;
        else
          Yrbf[(size_t)grow * 64 + (col - 64)] = v;
      }
    }
  }
}

// ---- ELL gather (R8 structure): 4 nodes/wave, 8-edge uint4 requests --------
// grp=lane>>3 picks one of 8 edge slots; sub=lane&7 picks a col octet
// (uint4 = 8 bf16). 4 independent accumulation chains. T written bf16.
__global__ __launch_bounds__(256) void gather_combine(
    const ushort* __restrict__ Ybf, const ushort* __restrict__ Yrbf,
    const int* __restrict__ ell, const int* __restrict__ deg,
    const float* __restrict__ bias, ushort* __restrict__ Tbf,
    float* __restrict__ stats, int n) {
  const int lane = threadIdx.x & 63;
  const int w = threadIdx.x >> 6;
  const int grp = lane >> 3;
  const int sub = lane & 7;
  const int wid = blockIdx.x * 4 + w;
  const int nw = gridDim.x * 4;
  float bc[8];
#pragma unroll
  for (int c = 0; c < 8; c++) bc[c] = bias[sub * 8 + c];
  float ssum[8], ssq[8];
#pragma unroll
  for (int c = 0; c < 8; c++) ssum[c] = ssq[c] = 0.f;

  for (int base = wid * 4; base < n; base += nw * 4) {
    int4 dg4 = *reinterpret_cast<const int4*>(deg + base);  // deg padded +4
    int dg[4] = {dg4.x, dg4.y, dg4.z, dg4.w};
    int cnt[4];
    int mx = 0;
#pragma unroll
    for (int j = 0; j < 4; j++) {
      cnt[j] = (base + j < n) ? min(dg[j], 64) : 0;
      mx = max(mx, cnt[j]);
    }
    float a[4][8];
#pragma unroll
    for (int j = 0; j < 4; j++)
#pragma unroll
      for (int c = 0; c < 8; c++) a[j][c] = 0.f;

    for (int e0 = 0; e0 < mx; e0 += 8) {
      int idx = e0 + grp;
      bool ok[4];
      int s[4];
#pragma unroll
      for (int j = 0; j < 4; j++) {
        ok[j] = idx < cnt[j];
        s[j] = ok[j] ? ell[(size_t)(base + j) * 64 + idx] : 0;
      }
      uint4 v[4];
#pragma unroll
      for (int j = 0; j < 4; j++)
        v[j] = *reinterpret_cast<const uint4*>(Ybf + (size_t)s[j] * 64 +
                                               sub * 8);
#pragma unroll
      for (int j = 0; j < 4; j++) {
        if (ok[j]) {
          float f[8];
          unpack8(v[j], f);
#pragma unroll
          for (int c = 0; c < 8; c++) a[j][c] += f[c];
        }
      }
    }
#pragma unroll
    for (int mmask = 8; mmask <= 32; mmask <<= 1)
#pragma unroll
      for (int j = 0; j < 4; j++)
#pragma unroll
        for (int c = 0; c < 8; c++)
          a[j][c] += __shfl_xor(a[j][c], mmask, 64);

    if (lane < 8) {  // grp == 0: finalize; lane sub owns cols sub*8..+7
#pragma unroll
      for (int j = 0; j < 4; j++) {
        int node = base + j;
        if (node >= n) continue;
        float iv = 1.0f / (float)max(dg[j], 1);
        uint4 yrv =
            *reinterpret_cast<const uint4*>(Yrbf + (size_t)node * 64 + sub * 8);
        float yr[8];
        unpack8(yrv, yr);
        float t[8];
#pragma unroll
        for (int c = 0; c < 8; c++) {
          t[c] = fmaf(a[j][c], iv, bc[c] + yr[c]);
          ssum[c] += t[c];
          ssq[c] = fmaf(t[c], t[c], ssq[c]);
        }
        uint4 o;
        o.x = (uint)f2bf(t[0]) | ((uint)f2bf(t[1]) << 16);
        o.y = (uint)f2bf(t[2]) | ((uint)f2bf(t[3]) << 16);
        o.z = (uint)f2bf(t[4]) | ((uint)f2bf(t[5]) << 16);
        o.w = (uint)f2bf(t[6]) | ((uint)f2bf(t[7]) << 16);
        *reinterpret_cast<uint4*>(Tbf + (size_t)node * 64 + sub * 8) = o;
      }
    }
  }
  __shared__ float rS[4][64];
  __shared__ float rQ[4][64];
  if (lane < 8) {
#pragma unroll
    for (int c = 0; c < 8; c++) {
      rS[w][sub * 8 + c] = ssum[c];
      rQ[w][sub * 8 + c] = ssq[c];
    }
  }
  __syncthreads();
  if (threadIdx.x < 64) {
    int tc = threadIdx.x;
    float s = rS[0][tc] + rS[1][tc] + rS[2][tc] + rS[3][tc];
    float qq = rQ[0][tc] + rQ[1][tc] + rQ[2][tc] + rQ[3][tc];
    atomicAdd(&stats[tc], s);
    atomicAdd(&stats[64 + tc], qq);
  }
}

// ---- BN finalize: ss[c]=scale, ss[64+c]=shift ------------------------------

__global__ void bn_finalize(const float* __restrict__ stats,
                            const float* __restrict__ g,
                            const float* __restrict__ be,
                            float* __restrict__ ss, int n) {
  int c = threadIdx.x;  // 64 threads
  float invn = 1.0f / (float)n;
  float mu = stats[c] * invn;
  float var = fmaf(-mu, mu, stats[64 + c] * invn);  // biased var
  float sc = g[c] * rsqrtf(var + 1e-5f);
  ss[c] = sc;
  ss[64 + c] = fmaf(-mu, sc, be[c]);
}

// ---- fusion MLP with layer-3 norm+ReLU fused in (T in bf16) ----------------

__global__ __launch_bounds__(256) void fusion_fused(
    const ushort* __restrict__ Tbf, const float* __restrict__ ss,
    const float* __restrict__ xgb, const float* __restrict__ Wf1,
    const float* __restrict__ bf1, const float* __restrict__ Wf2,
    const float* __restrict__ bf2, float* __restrict__ out, int n) {
  __shared__ float sH[64 * 64];
  __shared__ float sW1[65 * 64];
  __shared__ float sW2[64];
  const int tid = threadIdx.x;
  const int c = tid & 63;
  const int w = tid >> 6;
  const int row0 = blockIdx.x * 64;
  for (int i = tid; i < 65 * 64; i += 256) sW1[i] = Wf1[i];
  if (tid < 64) sW2[tid] = Wf2[tid];
  for (int i = tid; i < 512; i += 256) {
    int r = i >> 3;
    int k = (i & 7) * 8;
    int row = min(row0 + r, n - 1);
    uint4 v = *reinterpret_cast<const uint4*>(Tbf + (size_t)row * 64 + k);
    float f[8];
    unpack8(v, f);
#pragma unroll
    for (int j = 0; j < 8; j++)
      f[j] = fmaxf(fmaf(f[j], ss[k + j], ss[64 + k + j]), 0.f);
    *reinterpret_cast<float4*>(sH + r * 64 + k) =
        make_float4(f[0], f[1], f[2], f[3]);
    *reinterpret_cast<float4*>(sH + r * 64 + k + 4) =
        make_float4(f[4], f[5], f[6], f[7]);
  }
  __syncthreads();
  const float b1v = bf1[c];
  const float wx = sW1[64 * 64 + c];
  const float w2v = sW2[c];
  const float b2v = bf2[0];
  float acc[16];
#pragma unroll
  for (int r = 0; r < 16; r++) acc[r] = b1v;
  for (int kk = 0; kk < 64; kk += 4) {
    float4 hv[16];
#pragma unroll
    for (int r = 0; r < 16; r++)
      hv[r] = *reinterpret_cast<const float4*>(sH + (w * 16 + r) * 64 + kk);
    float w0 = sW1[(kk + 0) * 64 + c];
    float w1 = sW1[(kk + 1) * 64 + c];
    float w2 = sW1[(kk + 2) * 64 + c];
    float w3 = sW1[(kk + 3) * 64 + c];
#pragma unroll
    for (int r = 0; r < 16; r++) {
      acc[r] = fmaf(hv[r].x, w0, acc[r]);
      acc[r] = fmaf(hv[r].y, w1, acc[r]);
      acc[r] = fmaf(hv[r].z, w2, acc[r]);
      acc[r] = fmaf(hv[r].w, w3, acc[r]);
    }
  }
#pragma unroll
  for (int r = 0; r < 16; r++) {
    int row = row0 + w * 16 + r;
    float xv = (row < n) ? xgb[row] : 0.f;
    float z = fmaxf(fmaf(xv, wx, acc[r]), 0.f) * w2v;
#pragma unroll
    for (int off = 32; off > 0; off >>= 1) z += __shfl_xor(z, off, 64);
    if (row < n && c == 0) out[row] = z + b2v;
  }
}

// ---- launch ----------------------------------------------------------------

extern "C" void kernel_launch(void* const* d_in, const int* in_sizes, int n_in,
                              void* d_out, int out_size, void* d_ws,
                              size_t ws_size, hipStream_t stream) {
  const float* x = (const float*)d_in[0];
  const int* ei = (const int*)d_in[1];
  const float* xgb = (const float*)d_in[2];
  const float* W1l = (const float*)d_in[3];
  const float* b1 = (const float*)d_in[4];
  const float* W1r = (const float*)d_in[5];
  const float* g1 = (const float*)d_in[6];
  const float* be1 = (const float*)d_in[7];
  const float* W2l = (const float*)d_in[8];
  const float* b2 = (const float*)d_in[9];
  const float* W2r = (const float*)d_in[10];
  const float* g2 = (const float*)d_in[11];
  const float* be2 = (const float*)d_in[12];
  const float* W3l = (const float*)d_in[13];
  const float* b3 = (const float*)d_in[14];
  const float* W3r = (const float*)d_in[15];
  const float* g3 = (const float*)d_in[16];
  const float* be3 = (const float*)d_in[17];
  const float* Wf1 = (const float*)d_in[18];
  const float* bf1 = (const float*)d_in[19];
  const float* Wf2 = (const float*)d_in[20];
  const float* bf2 = (const float*)d_in[21];
  float* out = (float*)d_out;

  const int n = in_sizes[2];      // 100000
  const int E = in_sizes[1] / 2;  // 1200000

  char* w = (char*)d_ws;
  auto alloc = [&](size_t bytes) {
    void* p = (void*)w;
    w += (bytes + 255) & ~(size_t)255;
    return p;
  };
  int* deg = (int*)alloc((size_t)(n + 4) * 4);  // +4 pad for int4 tail read
  int* ell = (int*)alloc((size_t)n * 64 * 4);
  ushort* Ybf = (ushort*)alloc((size_t)n * 64 * 2);
  ushort* Yrbf = (ushort*)alloc((size_t)n * 64 * 2);
  ushort* Tbf = (ushort*)alloc((size_t)n * 64 * 2);
  ushort* Whi1 = (ushort*)alloc(128 * 128 * 2);
  ushort* Wlo1 = (ushort*)alloc(128 * 128 * 2);
  ushort* Whi2 = (ushort*)alloc(128 * 64 * 2);
  ushort* Wlo2 = (ushort*)alloc(128 * 64 * 2);
  ushort* Whi3 = (ushort*)alloc(128 * 64 * 2);
  ushort* Wlo3 = (ushort*)alloc(128 * 64 * 2);
  float* stats = (float*)alloc(3 * 128 * 4);
  float* ss = (float*)alloc(3 * 128 * 4);

  hipMemsetAsync(deg, 0, (size_t)(n + 4) * 4, stream);
  hipMemsetAsync(stats, 0, 3 * 128 * 4, stream);

  const int bps = 2048;
  ell_fill_sharded<<<16 * bps, 256, 0, stream>>>(ei, deg, ell, E, n, bps);
  prep_w<<<64, 256, 0, stream>>>(W1l, W1r, Whi1, Wlo1, 128);
  prep_w<<<32, 256, 0, stream>>>(W2l, W2r, Whi2, Wlo2, 64);
  prep_w<<<32, 256, 0, stream>>>(W3l, W3r, Whi3, Wlo3, 64);

  const int gTile = (n + 63) / 64;
  const int gGath = 2048;

  // ---- layer 1
  gemm_mfma<128, false, false><<<gTile, 256, 0, stream>>>(x, nullptr, Whi1,
                                                          Wlo1, Ybf, Yrbf, n);
  gather_combine<<<gGath, 256, 0, stream>>>(Ybf, Yrbf, ell, deg, b1, Tbf,
                                            stats + 0, n);
  bn_finalize<<<1, 64, 0, stream>>>(stats + 0, g1, be1, ss + 0, n);

  // ---- layer 2 (norm of T1 fused into GEMM staging)
  gemm_mfma<64, true, true><<<gTile, 256, 0, stream>>>(Tbf, ss + 0, Whi2, Wlo2,
                                                       Ybf, Yrbf, n);
  gather_combine<<<gGath, 256, 0, stream>>>(Ybf, Yrbf, ell, deg, b2, Tbf,
                                            stats + 128, n);
  bn_finalize<<<1, 64, 0, stream>>>(stats + 128, g2, be2, ss + 128, n);

  // ---- layer 3
  gemm_mfma<64, true, true><<<gTile, 256, 0, stream>>>(Tbf, ss + 128, Whi3,
                                                       Wlo3, Ybf, Yrbf, n);
  gather_combine<<<gGath, 256, 0, stream>>>(Ybf, Yrbf, ell, deg, b3, Tbf,
                                            stats + 256, n);
  bn_finalize<<<1, 64, 0, stream>>>(stats + 256, g3, be3, ss + 256, n);

  // ---- fusion MLP (norm of T3 fused in)
  fusion_fused<<<gTile, 256, 0, stream>>>(Tbf, ss + 256, xgb, Wf1, bf1, Wf2,
                                          bf2, out, n);
}

// Round 11
// 528.709 us; speedup vs baseline: 1.2165x; 1.0536x over previous
//
#include <hip/hip_runtime.h>

// ---------------------------------------------------------------------------
// HybridSAGEClassifier: 3x SAGEConv(mean) + BN + ReLU, then fusion MLP.
// R1: project-first (mean(x[src])@Wl == mean((x@Wl)[src])).
// R2: scatter-atomics -> CSR + register gather.
// R3: single-block scan -> 3-stage parallel scan.
// R4: register-blocked GEMM + norm/ReLU fused into consumers.
// R5: one-pass ELL; bf16 gather table.
// R6: MFMA 16x16x32_bf16, bf16x3 split (~fp32 accuracy).
// R7: gather: 4-node interleaved chains, 8-edge uint4 requests; Yr bf16.
// R8: ell_fill -> 16 temporally-sharded dst ranges (L2-resident writes).
// R9 FAILED: block-centric per-lane gather (exec-mask trip count, LDS-atomic
//     conflicts). R8 layout is the right structure for this table.
// R10: R8 gather + T in bf16 + XBF16 GEMM staging.
// R11: branch-free gather (ELL padded with sentinel row n -> no cnt/ok
//     predication; Ybf row n zeroed); bn_finalize folded into consumer
//     blocks (3 fewer launches). Gather treated as near its empirical
//     random-gather ceiling (~1.7 TB/s effective).
// ---------------------------------------------------------------------------

typedef __attribute__((ext_vector_type(8))) short bf16x8;
typedef __attribute__((ext_vector_type(4))) float f32x4;

__device__ __forceinline__ ushort f2bf(float f) {
  unsigned u = __float_as_uint(f);
  return (ushort)((u + 0x7fff + ((u >> 16) & 1)) >> 16);  // RNE
}
__device__ __forceinline__ float bf2f(ushort h) {
  return __uint_as_float((unsigned)h << 16);
}
__device__ __forceinline__ void unpack8(uint4 v, float* f) {
  f[0] = __uint_as_float(v.x << 16);
  f[1] = __uint_as_float(v.x & 0xffff0000u);
  f[2] = __uint_as_float(v.y << 16);
  f[3] = __uint_as_float(v.y & 0xffff0000u);
  f[4] = __uint_as_float(v.z << 16);
  f[5] = __uint_as_float(v.z & 0xffff0000u);
  f[6] = __uint_as_float(v.w << 16);
  f[7] = __uint_as_float(v.w & 0xffff0000u);
}

// ---- ELL init: fill with sentinel row index n (branch-free gather) ---------

__global__ __launch_bounds__(256) void ell_init(int4* __restrict__ ell,
                                                int val, int cnt4) {
  int i = blockIdx.x * 256 + threadIdx.x;
  if (i < cnt4) ell[i] = make_int4(val, val, val, val);
}

// ---- ELL build: temporally sharded scatter (R8) ----------------------------

__global__ __launch_bounds__(256) void ell_fill_sharded(
    const int* __restrict__ ei, int* __restrict__ deg, int* __restrict__ ell,
    int E, int n, int bps) {
  const int shard = blockIdx.x / bps;      // 0..15
  const int bib = blockIdx.x % bps;        // block-in-shard
  const int chunk = n >> 4;                // n/16
  const int lo = shard * chunk;
  const int hi = (shard == 15) ? n : lo + chunk;
  for (int e = bib * 256 + threadIdx.x; e < E; e += bps * 256) {
    int d = ei[E + e];
    if (d >= lo && d < hi) {
      int s = ei[e];
      int pos = atomicAdd(&deg[d], 1);
      if (pos < 64) ell[(size_t)d * 64 + pos] = s;
    }
  }
}

// ---- W prep: combined (Wl|Wr) -> col-major bf16 hi/lo ----------------------

__global__ void prep_w(const float* __restrict__ Wl,
                       const float* __restrict__ Wr, ushort* __restrict__ Whi,
                       ushort* __restrict__ Wlo, int din) {
  int i = blockIdx.x * blockDim.x + threadIdx.x;
  if (i >= 128 * din) return;
  int col = i / din, k = i % din;
  float v = (col < 64) ? Wl[(size_t)k * 64 + col]
                       : Wr[(size_t)k * 64 + (col - 64)];
  ushort h = f2bf(v);
  Whi[i] = h;
  Wlo[i] = f2bf(v - bf2f(h));
}

// ---- MFMA dual GEMM --------------------------------------------------------
// [Ybf | Yrbf] = f(X) @ [Wl | Wr]; f = BN(stats,g,be)+ReLU (NORM) or identity.
// BN scale/shift computed per block from raw stats (bn_finalize fused).
template <int DIN, bool NORM, bool XBF16>
__global__ __launch_bounds__(256) void gemm_mfma(
    const void* __restrict__ Xv, const float* __restrict__ stats,
    const float* __restrict__ g, const float* __restrict__ be,
    const ushort* __restrict__ Whi, const ushort* __restrict__ Wlo,
    ushort* __restrict__ Ybf, ushort* __restrict__ Yrbf, int n) {
  constexpr int XS = DIN + 4;
  constexpr int WS = 40;
  __shared__ float sX[64 * XS];
  __shared__ ushort sW[2 * 128 * WS];
  __shared__ float sSS[128];
  const int tid = threadIdx.x;
  const int w = tid >> 6;
  const int lane = tid & 63;
  const int m = lane & 15;
  const int quad = lane >> 4;
  const int row0 = blockIdx.x * 64;

  if (NORM) {
    if (tid < 64) {
      float invn = 1.0f / (float)n;
      float mu = stats[tid] * invn;
      float var = fmaf(-mu, mu, stats[64 + tid] * invn);
      float sc = g[tid] * rsqrtf(var + 1e-5f);
      sSS[tid] = sc;
      sSS[64 + tid] = fmaf(-mu, sc, be[tid]);
    }
    __syncthreads();
  }

  if (XBF16) {
    const ushort* X = (const ushort*)Xv;
    for (int i = tid; i < 64 * DIN / 8; i += 256) {
      int r = (i * 8) / DIN;
      int k = (i * 8) % DIN;
      int row = min(row0 + r, n - 1);
      uint4 v = *reinterpret_cast<const uint4*>(X + (size_t)row * DIN + k);
      float f[8];
      unpack8(v, f);
      if (NORM) {
#pragma unroll
        for (int j = 0; j < 8; j++)
          f[j] = fmaxf(fmaf(f[j], sSS[k + j], sSS[64 + k + j]), 0.f);
      }
      *reinterpret_cast<float4*>(sX + r * XS + k) =
          make_float4(f[0], f[1], f[2], f[3]);
      *reinterpret_cast<float4*>(sX + r * XS + k + 4) =
          make_float4(f[4], f[5], f[6], f[7]);
    }
  } else {
    const float* X = (const float*)Xv;
    for (int i = tid; i < 64 * DIN / 4; i += 256) {
      int r = (i * 4) / DIN;
      int k = (i * 4) % DIN;
      int row = min(row0 + r, n - 1);
      float4 v = *reinterpret_cast<const float4*>(X + (size_t)row * DIN + k);
      *reinterpret_cast<float4*>(sX + r * XS + k) = v;
    }
  }

  f32x4 acc[8];
#pragma unroll
  for (int t = 0; t < 8; t++) acc[t] = (f32x4){0.f, 0.f, 0.f, 0.f};

  for (int kc = 0; kc < DIN; kc += 32) {
    __syncthreads();
    for (int i = tid; i < 512; i += 256) {
      int col = i >> 2;
      int k = (i & 3) * 8;
      *reinterpret_cast<uint4*>(sW + col * WS + k) =
          *reinterpret_cast<const uint4*>(Whi + (size_t)col * DIN + kc + k);
      *reinterpret_cast<uint4*>(sW + 128 * WS + col * WS + k) =
          *reinterpret_cast<const uint4*>(Wlo + (size_t)col * DIN + kc + k);
    }
    __syncthreads();
    const float* ap = sX + (w * 16 + m) * XS + kc + quad * 8;
    float4 a0 = *reinterpret_cast<const float4*>(ap);
    float4 a1 = *reinterpret_cast<const float4*>(ap + 4);
    float av[8] = {a0.x, a0.y, a0.z, a0.w, a1.x, a1.y, a1.z, a1.w};
    bf16x8 Ahi, Alo;
#pragma unroll
    for (int j = 0; j < 8; j++) {
      ushort h = f2bf(av[j]);
      Ahi[j] = (short)h;
      Alo[j] = (short)f2bf(av[j] - bf2f(h));
    }
#pragma unroll
    for (int t = 0; t < 8; t++) {
      bf16x8 Bhi =
          *reinterpret_cast<const bf16x8*>(sW + (t * 16 + m) * WS + quad * 8);
      bf16x8 Blo = *reinterpret_cast<const bf16x8*>(sW + 128 * WS +
                                                    (t * 16 + m) * WS +
                                                    quad * 8);
      acc[t] = __builtin_amdgcn_mfma_f32_16x16x32_bf16(Ahi, Bhi, acc[t], 0, 0, 0);
      acc[t] = __builtin_amdgcn_mfma_f32_16x16x32_bf16(Ahi, Blo, acc[t], 0, 0, 0);
      acc[t] = __builtin_amdgcn_mfma_f32_16x16x32_bf16(Alo, Bhi, acc[t], 0, 0, 0);
    }
  }

#pragma unroll
  for (int t = 0; t < 8; t++) {
    int col = t * 16 + m;
#pragma unroll
    for (int r = 0; r < 4; r++) {
      int grow = row0 + w * 16 + quad * 4 + r;
      if (grow < n) {
        ushort v = f2bf(acc[t][r]);
        if (t < 4)
          Ybf[(size_t)grow * 64 + col] = v;
        else
          Yrbf[(size_t)grow * 64 + (col - 64)] = v;
      }
    }
  }
}

// ---- ELL gather (R8 structure, branch-free): 4 nodes/wave, 8-edge slots ----
// Pad slots hold sentinel n -> Ybf row n is zero -> unconditional accumulate.
__global__ __launch_bounds__(256) void gather_combine(
    const ushort* __restrict__ Ybf, const ushort* __restrict__ Yrbf,
    const int* __restrict__ ell, const int* __restrict__ deg,
    const float* __restrict__ bias, ushort* __restrict__ Tbf,
    float* __restrict__ stats, int n) {
  const int lane = threadIdx.x & 63;
  const int w = threadIdx.x >> 6;
  const int grp = lane >> 3;
  const int sub = lane & 7;
  const int wid = blockIdx.x * 4 + w;
  const int nw = gridDim.x * 4;
  float bc[8];
#pragma unroll
  for (int c = 0; c < 8; c++) bc[c] = bias[sub * 8 + c];
  float ssum[8], ssq[8];
#pragma unroll
  for (int c = 0; c < 8; c++) ssum[c] = ssq[c] = 0.f;

  for (int base = wid * 4; base < n; base += nw * 4) {
    int4 dg4 = *reinterpret_cast<const int4*>(deg + base);  // deg padded +4
    int dg[4] = {dg4.x, dg4.y, dg4.z, dg4.w};
    int mx = 0;
#pragma unroll
    for (int j = 0; j < 4; j++) mx = max(mx, min(dg[j], 64));
    float a[4][8];
#pragma unroll
    for (int j = 0; j < 4; j++)
#pragma unroll
      for (int c = 0; c < 8; c++) a[j][c] = 0.f;

    for (int e0 = 0; e0 < mx; e0 += 8) {
      int idx = e0 + grp;
      int s0 = ell[(size_t)(base + 0) * 64 + idx];
      int s1 = ell[(size_t)(base + 1) * 64 + idx];
      int s2 = ell[(size_t)(base + 2) * 64 + idx];
      int s3 = ell[(size_t)(base + 3) * 64 + idx];
      uint4 v0 = *reinterpret_cast<const uint4*>(Ybf + (size_t)s0 * 64 + sub * 8);
      uint4 v1 = *reinterpret_cast<const uint4*>(Ybf + (size_t)s1 * 64 + sub * 8);
      uint4 v2 = *reinterpret_cast<const uint4*>(Ybf + (size_t)s2 * 64 + sub * 8);
      uint4 v3 = *reinterpret_cast<const uint4*>(Ybf + (size_t)s3 * 64 + sub * 8);
      float f[8];
      unpack8(v0, f);
#pragma unroll
      for (int c = 0; c < 8; c++) a[0][c] += f[c];
      unpack8(v1, f);
#pragma unroll
      for (int c = 0; c < 8; c++) a[1][c] += f[c];
      unpack8(v2, f);
#pragma unroll
      for (int c = 0; c < 8; c++) a[2][c] += f[c];
      unpack8(v3, f);
#pragma unroll
      for (int c = 0; c < 8; c++) a[3][c] += f[c];
    }
#pragma unroll
    for (int mmask = 8; mmask <= 32; mmask <<= 1)
#pragma unroll
      for (int j = 0; j < 4; j++)
#pragma unroll
        for (int c = 0; c < 8; c++)
          a[j][c] += __shfl_xor(a[j][c], mmask, 64);

    if (lane < 8) {  // grp == 0: finalize; lane sub owns cols sub*8..+7
#pragma unroll
      for (int j = 0; j < 4; j++) {
        int node = base + j;
        if (node >= n) continue;
        float iv = 1.0f / (float)max(dg[j], 1);
        uint4 yrv =
            *reinterpret_cast<const uint4*>(Yrbf + (size_t)node * 64 + sub * 8);
        float yr[8];
        unpack8(yrv, yr);
        float t[8];
#pragma unroll
        for (int c = 0; c < 8; c++) {
          t[c] = fmaf(a[j][c], iv, bc[c] + yr[c]);
          ssum[c] += t[c];
          ssq[c] = fmaf(t[c], t[c], ssq[c]);
        }
        uint4 o;
        o.x = (uint)f2bf(t[0]) | ((uint)f2bf(t[1]) << 16);
        o.y = (uint)f2bf(t[2]) | ((uint)f2bf(t[3]) << 16);
        o.z = (uint)f2bf(t[4]) | ((uint)f2bf(t[5]) << 16);
        o.w = (uint)f2bf(t[6]) | ((uint)f2bf(t[7]) << 16);
        *reinterpret_cast<uint4*>(Tbf + (size_t)node * 64 + sub * 8) = o;
      }
    }
  }
  __shared__ float rS[4][64];
  __shared__ float rQ[4][64];
  if (lane < 8) {
#pragma unroll
    for (int c = 0; c < 8; c++) {
      rS[w][sub * 8 + c] = ssum[c];
      rQ[w][sub * 8 + c] = ssq[c];
    }
  }
  __syncthreads();
  if (threadIdx.x < 64) {
    int tc = threadIdx.x;
    float s = rS[0][tc] + rS[1][tc] + rS[2][tc] + rS[3][tc];
    float qq = rQ[0][tc] + rQ[1][tc] + rQ[2][tc] + rQ[3][tc];
    atomicAdd(&stats[tc], s);
    atomicAdd(&stats[64 + tc], qq);
  }
}

// ---- fusion MLP: layer-3 BN (from raw stats) + ReLU fused, T in bf16 -------

__global__ __launch_bounds__(256) void fusion_fused(
    const ushort* __restrict__ Tbf, const float* __restrict__ stats,
    const float* __restrict__ g, const float* __restrict__ be,
    const float* __restrict__ xgb, const float* __restrict__ Wf1,
    const float* __restrict__ bf1, const float* __restrict__ Wf2,
    const float* __restrict__ bf2, float* __restrict__ out, int n) {
  __shared__ float sH[64 * 64];
  __shared__ float sW1[65 * 64];
  __shared__ float sW2[64];
  __shared__ float sSS[128];
  const int tid = threadIdx.x;
  const int c = tid & 63;
  const int w = tid >> 6;
  const int row0 = blockIdx.x * 64;
  if (tid < 64) {
    float invn = 1.0f / (float)n;
    float mu = stats[tid] * invn;
    float var = fmaf(-mu, mu, stats[64 + tid] * invn);
    float sc = g[tid] * rsqrtf(var + 1e-5f);
    sSS[tid] = sc;
    sSS[64 + tid] = fmaf(-mu, sc, be[tid]);
  }
  for (int i = tid; i < 65 * 64; i += 256) sW1[i] = Wf1[i];
  if (tid < 64) sW2[tid] = Wf2[tid];
  __syncthreads();
  for (int i = tid; i < 512; i += 256) {
    int r = i >> 3;
    int k = (i & 7) * 8;
    int row = min(row0 + r, n - 1);
    uint4 v = *reinterpret_cast<const uint4*>(Tbf + (size_t)row * 64 + k);
    float f[8];
    unpack8(v, f);
#pragma unroll
    for (int j = 0; j < 8; j++)
      f[j] = fmaxf(fmaf(f[j], sSS[k + j], sSS[64 + k + j]), 0.f);
    *reinterpret_cast<float4*>(sH + r * 64 + k) =
        make_float4(f[0], f[1], f[2], f[3]);
    *reinterpret_cast<float4*>(sH + r * 64 + k + 4) =
        make_float4(f[4], f[5], f[6], f[7]);
  }
  __syncthreads();
  const float b1v = bf1[c];
  const float wx = sW1[64 * 64 + c];
  const float w2v = sW2[c];
  const float b2v = bf2[0];
  float acc[16];
#pragma unroll
  for (int r = 0; r < 16; r++) acc[r] = b1v;
  for (int kk = 0; kk < 64; kk += 4) {
    float4 hv[16];
#pragma unroll
    for (int r = 0; r < 16; r++)
      hv[r] = *reinterpret_cast<const float4*>(sH + (w * 16 + r) * 64 + kk);
    float w0 = sW1[(kk + 0) * 64 + c];
    float w1 = sW1[(kk + 1) * 64 + c];
    float w2 = sW1[(kk + 2) * 64 + c];
    float w3 = sW1[(kk + 3) * 64 + c];
#pragma unroll
    for (int r = 0; r < 16; r++) {
      acc[r] = fmaf(hv[r].x, w0, acc[r]);
      acc[r] = fmaf(hv[r].y, w1, acc[r]);
      acc[r] = fmaf(hv[r].z, w2, acc[r]);
      acc[r] = fmaf(hv[r].w, w3, acc[r]);
    }
  }
#pragma unroll
  for (int r = 0; r < 16; r++) {
    int row = row0 + w * 16 + r;
    float xv = (row < n) ? xgb[row] : 0.f;
    float z = fmaxf(fmaf(xv, wx, acc[r]), 0.f) * w2v;
#pragma unroll
    for (int off = 32; off > 0; off >>= 1) z += __shfl_xor(z, off, 64);
    if (row < n && c == 0) out[row] = z + b2v;
  }
}

// ---- launch ----------------------------------------------------------------

extern "C" void kernel_launch(void* const* d_in, const int* in_sizes, int n_in,
                              void* d_out, int out_size, void* d_ws,
                              size_t ws_size, hipStream_t stream) {
  const float* x = (const float*)d_in[0];
  const int* ei = (const int*)d_in[1];
  const float* xgb = (const float*)d_in[2];
  const float* W1l = (const float*)d_in[3];
  const float* b1 = (const float*)d_in[4];
  const float* W1r = (const float*)d_in[5];
  const float* g1 = (const float*)d_in[6];
  const float* be1 = (const float*)d_in[7];
  const float* W2l = (const float*)d_in[8];
  const float* b2 = (const float*)d_in[9];
  const float* W2r = (const float*)d_in[10];
  const float* g2 = (const float*)d_in[11];
  const float* be2 = (const float*)d_in[12];
  const float* W3l = (const float*)d_in[13];
  const float* b3 = (const float*)d_in[14];
  const float* W3r = (const float*)d_in[15];
  const float* g3 = (const float*)d_in[16];
  const float* be3 = (const float*)d_in[17];
  const float* Wf1 = (const float*)d_in[18];
  const float* bf1 = (const float*)d_in[19];
  const float* Wf2 = (const float*)d_in[20];
  const float* bf2 = (const float*)d_in[21];
  float* out = (float*)d_out;

  const int n = in_sizes[2];      // 100000
  const int E = in_sizes[1] / 2;  // 1200000

  char* w = (char*)d_ws;
  auto alloc = [&](size_t bytes) {
    void* p = (void*)w;
    w += (bytes + 255) & ~(size_t)255;
    return p;
  };
  int* deg = (int*)alloc((size_t)(n + 4) * 4);        // +4 pad for int4 tail
  int* ell = (int*)alloc((size_t)(n + 4) * 64 * 4);   // +4 pad rows
  ushort* Ybf = (ushort*)alloc((size_t)(n + 1) * 64 * 2);  // +1 zero row
  ushort* Yrbf = (ushort*)alloc((size_t)n * 64 * 2);
  ushort* Tbf = (ushort*)alloc((size_t)n * 64 * 2);
  ushort* Whi1 = (ushort*)alloc(128 * 128 * 2);
  ushort* Wlo1 = (ushort*)alloc(128 * 128 * 2);
  ushort* Whi2 = (ushort*)alloc(128 * 64 * 2);
  ushort* Wlo2 = (ushort*)alloc(128 * 64 * 2);
  ushort* Whi3 = (ushort*)alloc(128 * 64 * 2);
  ushort* Wlo3 = (ushort*)alloc(128 * 64 * 2);
  float* stats = (float*)alloc(3 * 128 * 4);

  hipMemsetAsync(deg, 0, (size_t)(n + 4) * 4, stream);
  hipMemsetAsync(stats, 0, 3 * 128 * 4, stream);
  hipMemsetAsync(Ybf + (size_t)n * 64, 0, 128, stream);  // zero sentinel row

  const int cnt4 = (n + 4) * 16;  // (n+4)*64/4 int4s
  ell_init<<<(cnt4 + 255) / 256, 256, 0, stream>>>((int4*)ell, n, cnt4);
  const int bps = 2048;
  ell_fill_sharded<<<16 * bps, 256, 0, stream>>>(ei, deg, ell, E, n, bps);
  prep_w<<<64, 256, 0, stream>>>(W1l, W1r, Whi1, Wlo1, 128);
  prep_w<<<32, 256, 0, stream>>>(W2l, W2r, Whi2, Wlo2, 64);
  prep_w<<<32, 256, 0, stream>>>(W3l, W3r, Whi3, Wlo3, 64);

  const int gTile = (n + 63) / 64;
  const int gGath = 2048;

  // ---- layer 1
  gemm_mfma<128, false, false><<<gTile, 256, 0, stream>>>(
      x, nullptr, nullptr, nullptr, Whi1, Wlo1, Ybf, Yrbf, n);
  gather_combine<<<gGath, 256, 0, stream>>>(Ybf, Yrbf, ell, deg, b1, Tbf,
                                            stats + 0, n);

  // ---- layer 2 (BN1 finalize + norm fused into GEMM staging)
  gemm_mfma<64, true, true><<<gTile, 256, 0, stream>>>(
      Tbf, stats + 0, g1, be1, Whi2, Wlo2, Ybf, Yrbf, n);
  gather_combine<<<gGath, 256, 0, stream>>>(Ybf, Yrbf, ell, deg, b2, Tbf,
                                            stats + 128, n);

  // ---- layer 3
  gemm_mfma<64, true, true><<<gTile, 256, 0, stream>>>(
      Tbf, stats + 128, g2, be2, Whi3, Wlo3, Ybf, Yrbf, n);
  gather_combine<<<gGath, 256, 0, stream>>>(Ybf, Yrbf, ell, deg, b3, Tbf,
                                            stats + 256, n);

  // ---- fusion MLP (BN3 finalize + norm fused in)
  fusion_fused<<<gTile, 256, 0, stream>>>(Tbf, stats + 256, g3, be3, xgb, Wf1,
                                          bf1, Wf2, bf2, out, n);
}

// Round 12
// 512.802 us; speedup vs baseline: 1.2542x; 1.0310x over previous
//
#include <hip/hip_runtime.h>

// ---------------------------------------------------------------------------
// HybridSAGEClassifier: 3x SAGEConv(mean) + BN + ReLU, then fusion MLP.
// R1: project-first (mean(x[src])@Wl == mean((x@Wl)[src])).
// R2: scatter-atomics -> CSR + register gather.
// R3: single-block scan -> 3-stage parallel scan.
// R4: register-blocked GEMM + norm/ReLU fused into consumers.
// R5: one-pass ELL; bf16 gather table.
// R6: MFMA 16x16x32_bf16, bf16x3 split (~fp32 accuracy).
// R7: gather: 4-node interleaved chains, 8-edge uint4 requests; Yr bf16.
// R8: ell_fill -> 16 temporally-sharded dst ranges (L2-resident writes).
// R9 FAILED: block-centric per-lane gather. R8 layout is right for this.
// R10: R8 gather + T in bf16 + XBF16 GEMM staging.
// R11: branch-free gather (sentinel row); bn_finalize fused into consumers.
// R12: gemm sX LDS tile had ZERO reuse (each element read once by one wave)
//      -> direct global A-fragment loads (L1-resident working set), LDS
//      54KB->21KB, 2->5+ blocks/CU; ELL stride 64->48 (P(deg>=48)~1e-15).
//      Gather at its measured random-row service floor (~78us).
// ---------------------------------------------------------------------------

typedef __attribute__((ext_vector_type(8))) short bf16x8;
typedef __attribute__((ext_vector_type(4))) float f32x4;

#define ELLS 48  // ELL row stride

__device__ __forceinline__ ushort f2bf(float f) {
  unsigned u = __float_as_uint(f);
  return (ushort)((u + 0x7fff + ((u >> 16) & 1)) >> 16);  // RNE
}
__device__ __forceinline__ float bf2f(ushort h) {
  return __uint_as_float((unsigned)h << 16);
}
__device__ __forceinline__ void unpack8(uint4 v, float* f) {
  f[0] = __uint_as_float(v.x << 16);
  f[1] = __uint_as_float(v.x & 0xffff0000u);
  f[2] = __uint_as_float(v.y << 16);
  f[3] = __uint_as_float(v.y & 0xffff0000u);
  f[4] = __uint_as_float(v.z << 16);
  f[5] = __uint_as_float(v.z & 0xffff0000u);
  f[6] = __uint_as_float(v.w << 16);
  f[7] = __uint_as_float(v.w & 0xffff0000u);
}

// ---- ELL init: fill with sentinel row index n ------------------------------

__global__ __launch_bounds__(256) void ell_init(int4* __restrict__ ell,
                                                int val, int cnt4) {
  int i = blockIdx.x * 256 + threadIdx.x;
  if (i < cnt4) ell[i] = make_int4(val, val, val, val);
}

// ---- ELL build: temporally sharded scatter (R8) ----------------------------

__global__ __launch_bounds__(256) void ell_fill_sharded(
    const int* __restrict__ ei, int* __restrict__ deg, int* __restrict__ ell,
    int E, int n, int bps) {
  const int shard = blockIdx.x / bps;      // 0..15
  const int bib = blockIdx.x % bps;        // block-in-shard
  const int chunk = n >> 4;                // n/16
  const int lo = shard * chunk;
  const int hi = (shard == 15) ? n : lo + chunk;
  for (int e = bib * 256 + threadIdx.x; e < E; e += bps * 256) {
    int d = ei[E + e];
    if (d >= lo && d < hi) {
      int s = ei[e];
      int pos = atomicAdd(&deg[d], 1);
      if (pos < ELLS) ell[(size_t)d * ELLS + pos] = s;
    }
  }
}

// ---- W prep: combined (Wl|Wr) -> col-major bf16 hi/lo ----------------------

__global__ void prep_w(const float* __restrict__ Wl,
                       const float* __restrict__ Wr, ushort* __restrict__ Whi,
                       ushort* __restrict__ Wlo, int din) {
  int i = blockIdx.x * blockDim.x + threadIdx.x;
  if (i >= 128 * din) return;
  int col = i / din, k = i % din;
  float v = (col < 64) ? Wl[(size_t)k * 64 + col]
                       : Wr[(size_t)k * 64 + (col - 64)];
  ushort h = f2bf(v);
  Whi[i] = h;
  Wlo[i] = f2bf(v - bf2f(h));
}

// ---- MFMA dual GEMM (direct global A-loads, no sX) -------------------------
// [Ybf | Yrbf] = f(X) @ [Wl | Wr]; f = BN(stats,g,be)+ReLU (NORM) or identity.
// A-fragment loaded straight from global at (row=w*16+m, cols kc+quad*8..+7);
// each wave's 16-row working set is L1-resident. Only W staged in LDS.
template <int DIN, bool NORM, bool XBF16>
__global__ __launch_bounds__(256) void gemm_mfma(
    const void* __restrict__ Xv, const float* __restrict__ stats,
    const float* __restrict__ g, const float* __restrict__ be,
    const ushort* __restrict__ Whi, const ushort* __restrict__ Wlo,
    ushort* __restrict__ Ybf, ushort* __restrict__ Yrbf, int n) {
  constexpr int WS = 40;
  __shared__ ushort sW[2 * 128 * WS];
  __shared__ float sSS[128];
  const int tid = threadIdx.x;
  const int w = tid >> 6;
  const int lane = tid & 63;
  const int m = lane & 15;
  const int quad = lane >> 4;
  const int row0 = blockIdx.x * 64;

  if (NORM) {
    if (tid < 64) {
      float invn = 1.0f / (float)n;
      float mu = stats[tid] * invn;
      float var = fmaf(-mu, mu, stats[64 + tid] * invn);
      float sc = g[tid] * rsqrtf(var + 1e-5f);
      sSS[tid] = sc;
      sSS[64 + tid] = fmaf(-mu, sc, be[tid]);
    }
  }

  const int arow = min(row0 + w * 16 + m, n - 1);

  f32x4 acc[8];
#pragma unroll
  for (int t = 0; t < 8; t++) acc[t] = (f32x4){0.f, 0.f, 0.f, 0.f};

  for (int kc = 0; kc < DIN; kc += 32) {
    __syncthreads();  // prev sW reads done / sSS ready (first iter)
    for (int i = tid; i < 512; i += 256) {
      int col = i >> 2;
      int k = (i & 3) * 8;
      *reinterpret_cast<uint4*>(sW + col * WS + k) =
          *reinterpret_cast<const uint4*>(Whi + (size_t)col * DIN + kc + k);
      *reinterpret_cast<uint4*>(sW + 128 * WS + col * WS + k) =
          *reinterpret_cast<const uint4*>(Wlo + (size_t)col * DIN + kc + k);
    }
    __syncthreads();

    // A fragment: direct global load
    const int kb = kc + quad * 8;
    float av[8];
    if (XBF16) {
      const ushort* X = (const ushort*)Xv;
      uint4 v = *reinterpret_cast<const uint4*>(X + (size_t)arow * DIN + kb);
      unpack8(v, av);
    } else {
      const float* X = (const float*)Xv;
      const float* ap = X + (size_t)arow * DIN + kb;
      float4 a0 = *reinterpret_cast<const float4*>(ap);
      float4 a1 = *reinterpret_cast<const float4*>(ap + 4);
      av[0] = a0.x; av[1] = a0.y; av[2] = a0.z; av[3] = a0.w;
      av[4] = a1.x; av[5] = a1.y; av[6] = a1.z; av[7] = a1.w;
    }
    if (NORM) {
#pragma unroll
      for (int j = 0; j < 8; j++)
        av[j] = fmaxf(fmaf(av[j], sSS[kb + j], sSS[64 + kb + j]), 0.f);
    }
    bf16x8 Ahi, Alo;
#pragma unroll
    for (int j = 0; j < 8; j++) {
      ushort h = f2bf(av[j]);
      Ahi[j] = (short)h;
      Alo[j] = (short)f2bf(av[j] - bf2f(h));
    }
#pragma unroll
    for (int t = 0; t < 8; t++) {
      bf16x8 Bhi =
          *reinterpret_cast<const bf16x8*>(sW + (t * 16 + m) * WS + quad * 8);
      bf16x8 Blo = *reinterpret_cast<const bf16x8*>(sW + 128 * WS +
                                                    (t * 16 + m) * WS +
                                                    quad * 8);
      acc[t] = __builtin_amdgcn_mfma_f32_16x16x32_bf16(Ahi, Bhi, acc[t], 0, 0, 0);
      acc[t] = __builtin_amdgcn_mfma_f32_16x16x32_bf16(Ahi, Blo, acc[t], 0, 0, 0);
      acc[t] = __builtin_amdgcn_mfma_f32_16x16x32_bf16(Alo, Bhi, acc[t], 0, 0, 0);
    }
  }

#pragma unroll
  for (int t = 0; t < 8; t++) {
    int col = t * 16 + m;
#pragma unroll
    for (int r = 0; r < 4; r++) {
      int grow = row0 + w * 16 + quad * 4 + r;
      if (grow < n) {
        ushort v = f2bf(acc[t][r]);
        if (t < 4)
          Ybf[(size_t)grow * 64 + col] = v;
        else
          Yrbf[(size_t)grow * 64 + (col - 64)] = v;
      }
    }
  }
}

// ---- ELL gather (R11): branch-free, 4 nodes/wave, 8-edge slots -------------

__global__ __launch_bounds__(256) void gather_combine(
    const ushort* __restrict__ Ybf, const ushort* __restrict__ Yrbf,
    const int* __restrict__ ell, const int* __restrict__ deg,
    const float* __restrict__ bias, ushort* __restrict__ Tbf,
    float* __restrict__ stats, int n) {
  const int lane = threadIdx.x & 63;
  const int w = threadIdx.x >> 6;
  const int grp = lane >> 3;
  const int sub = lane & 7;
  const int wid = blockIdx.x * 4 + w;
  const int nw = gridDim.x * 4;
  float bc[8];
#pragma unroll
  for (int c = 0; c < 8; c++) bc[c] = bias[sub * 8 + c];
  float ssum[8], ssq[8];
#pragma unroll
  for (int c = 0; c < 8; c++) ssum[c] = ssq[c] = 0.f;

  for (int base = wid * 4; base < n; base += nw * 4) {
    int4 dg4 = *reinterpret_cast<const int4*>(deg + base);  // deg padded +4
    int dg[4] = {dg4.x, dg4.y, dg4.z, dg4.w};
    int mx = 0;
#pragma unroll
    for (int j = 0; j < 4; j++) mx = max(mx, min(dg[j], ELLS));
    float a[4][8];
#pragma unroll
    for (int j = 0; j < 4; j++)
#pragma unroll
      for (int c = 0; c < 8; c++) a[j][c] = 0.f;

    for (int e0 = 0; e0 < mx; e0 += 8) {
      int idx = e0 + grp;
      int s0 = ell[(size_t)(base + 0) * ELLS + idx];
      int s1 = ell[(size_t)(base + 1) * ELLS + idx];
      int s2 = ell[(size_t)(base + 2) * ELLS + idx];
      int s3 = ell[(size_t)(base + 3) * ELLS + idx];
      uint4 v0 = *reinterpret_cast<const uint4*>(Ybf + (size_t)s0 * 64 + sub * 8);
      uint4 v1 = *reinterpret_cast<const uint4*>(Ybf + (size_t)s1 * 64 + sub * 8);
      uint4 v2 = *reinterpret_cast<const uint4*>(Ybf + (size_t)s2 * 64 + sub * 8);
      uint4 v3 = *reinterpret_cast<const uint4*>(Ybf + (size_t)s3 * 64 + sub * 8);
      float f[8];
      unpack8(v0, f);
#pragma unroll
      for (int c = 0; c < 8; c++) a[0][c] += f[c];
      unpack8(v1, f);
#pragma unroll
      for (int c = 0; c < 8; c++) a[1][c] += f[c];
      unpack8(v2, f);
#pragma unroll
      for (int c = 0; c < 8; c++) a[2][c] += f[c];
      unpack8(v3, f);
#pragma unroll
      for (int c = 0; c < 8; c++) a[3][c] += f[c];
    }
#pragma unroll
    for (int mmask = 8; mmask <= 32; mmask <<= 1)
#pragma unroll
      for (int j = 0; j < 4; j++)
#pragma unroll
        for (int c = 0; c < 8; c++)
          a[j][c] += __shfl_xor(a[j][c], mmask, 64);

    if (lane < 8) {  // grp == 0: finalize; lane sub owns cols sub*8..+7
#pragma unroll
      for (int j = 0; j < 4; j++) {
        int node = base + j;
        if (node >= n) continue;
        float iv = 1.0f / (float)max(dg[j], 1);
        uint4 yrv =
            *reinterpret_cast<const uint4*>(Yrbf + (size_t)node * 64 + sub * 8);
        float yr[8];
        unpack8(yrv, yr);
        float t[8];
#pragma unroll
        for (int c = 0; c < 8; c++) {
          t[c] = fmaf(a[j][c], iv, bc[c] + yr[c]);
          ssum[c] += t[c];
          ssq[c] = fmaf(t[c], t[c], ssq[c]);
        }
        uint4 o;
        o.x = (uint)f2bf(t[0]) | ((uint)f2bf(t[1]) << 16);
        o.y = (uint)f2bf(t[2]) | ((uint)f2bf(t[3]) << 16);
        o.z = (uint)f2bf(t[4]) | ((uint)f2bf(t[5]) << 16);
        o.w = (uint)f2bf(t[6]) | ((uint)f2bf(t[7]) << 16);
        *reinterpret_cast<uint4*>(Tbf + (size_t)node * 64 + sub * 8) = o;
      }
    }
  }
  __shared__ float rS[4][64];
  __shared__ float rQ[4][64];
  if (lane < 8) {
#pragma unroll
    for (int c = 0; c < 8; c++) {
      rS[w][sub * 8 + c] = ssum[c];
      rQ[w][sub * 8 + c] = ssq[c];
    }
  }
  __syncthreads();
  if (threadIdx.x < 64) {
    int tc = threadIdx.x;
    float s = rS[0][tc] + rS[1][tc] + rS[2][tc] + rS[3][tc];
    float qq = rQ[0][tc] + rQ[1][tc] + rQ[2][tc] + rQ[3][tc];
    atomicAdd(&stats[tc], s);
    atomicAdd(&stats[64 + tc], qq);
  }
}

// ---- fusion MLP: layer-3 BN (from raw stats) + ReLU fused, T in bf16 -------

__global__ __launch_bounds__(256) void fusion_fused(
    const ushort* __restrict__ Tbf, const float* __restrict__ stats,
    const float* __restrict__ g, const float* __restrict__ be,
    const float* __restrict__ xgb, const float* __restrict__ Wf1,
    const float* __restrict__ bf1, const float* __restrict__ Wf2,
    const float* __restrict__ bf2, float* __restrict__ out, int n) {
  __shared__ float sH[64 * 64];
  __shared__ float sW1[65 * 64];
  __shared__ float sW2[64];
  __shared__ float sSS[128];
  const int tid = threadIdx.x;
  const int c = tid & 63;
  const int w = tid >> 6;
  const int row0 = blockIdx.x * 64;
  if (tid < 64) {
    float invn = 1.0f / (float)n;
    float mu = stats[tid] * invn;
    float var = fmaf(-mu, mu, stats[64 + tid] * invn);
    float sc = g[tid] * rsqrtf(var + 1e-5f);
    sSS[tid] = sc;
    sSS[64 + tid] = fmaf(-mu, sc, be[tid]);
  }
  for (int i = tid; i < 65 * 64; i += 256) sW1[i] = Wf1[i];
  if (tid < 64) sW2[tid] = Wf2[tid];
  __syncthreads();
  for (int i = tid; i < 512; i += 256) {
    int r = i >> 3;
    int k = (i & 7) * 8;
    int row = min(row0 + r, n - 1);
    uint4 v = *reinterpret_cast<const uint4*>(Tbf + (size_t)row * 64 + k);
    float f[8];
    unpack8(v, f);
#pragma unroll
    for (int j = 0; j < 8; j++)
      f[j] = fmaxf(fmaf(f[j], sSS[k + j], sSS[64 + k + j]), 0.f);
    *reinterpret_cast<float4*>(sH + r * 64 + k) =
        make_float4(f[0], f[1], f[2], f[3]);
    *reinterpret_cast<float4*>(sH + r * 64 + k + 4) =
        make_float4(f[4], f[5], f[6], f[7]);
  }
  __syncthreads();
  const float b1v = bf1[c];
  const float wx = sW1[64 * 64 + c];
  const float w2v = sW2[c];
  const float b2v = bf2[0];
  float acc[16];
#pragma unroll
  for (int r = 0; r < 16; r++) acc[r] = b1v;
  for (int kk = 0; kk < 64; kk += 4) {
    float4 hv[16];
#pragma unroll
    for (int r = 0; r < 16; r++)
      hv[r] = *reinterpret_cast<const float4*>(sH + (w * 16 + r) * 64 + kk);
    float w0 = sW1[(kk + 0) * 64 + c];
    float w1 = sW1[(kk + 1) * 64 + c];
    float w2 = sW1[(kk + 2) * 64 + c];
    float w3 = sW1[(kk + 3) * 64 + c];
#pragma unroll
    for (int r = 0; r < 16; r++) {
      acc[r] = fmaf(hv[r].x, w0, acc[r]);
      acc[r] = fmaf(hv[r].y, w1, acc[r]);
      acc[r] = fmaf(hv[r].z, w2, acc[r]);
      acc[r] = fmaf(hv[r].w, w3, acc[r]);
    }
  }
#pragma unroll
  for (int r = 0; r < 16; r++) {
    int row = row0 + w * 16 + r;
    float xv = (row < n) ? xgb[row] : 0.f;
    float z = fmaxf(fmaf(xv, wx, acc[r]), 0.f) * w2v;
#pragma unroll
    for (int off = 32; off > 0; off >>= 1) z += __shfl_xor(z, off, 64);
    if (row < n && c == 0) out[row] = z + b2v;
  }
}

// ---- launch ----------------------------------------------------------------

extern "C" void kernel_launch(void* const* d_in, const int* in_sizes, int n_in,
                              void* d_out, int out_size, void* d_ws,
                              size_t ws_size, hipStream_t stream) {
  const float* x = (const float*)d_in[0];
  const int* ei = (const int*)d_in[1];
  const float* xgb = (const float*)d_in[2];
  const float* W1l = (const float*)d_in[3];
  const float* b1 = (const float*)d_in[4];
  const float* W1r = (const float*)d_in[5];
  const float* g1 = (const float*)d_in[6];
  const float* be1 = (const float*)d_in[7];
  const float* W2l = (const float*)d_in[8];
  const float* b2 = (const float*)d_in[9];
  const float* W2r = (const float*)d_in[10];
  const float* g2 = (const float*)d_in[11];
  const float* be2 = (const float*)d_in[12];
  const float* W3l = (const float*)d_in[13];
  const float* b3 = (const float*)d_in[14];
  const float* W3r = (const float*)d_in[15];
  const float* g3 = (const float*)d_in[16];
  const float* be3 = (const float*)d_in[17];
  const float* Wf1 = (const float*)d_in[18];
  const float* bf1 = (const float*)d_in[19];
  const float* Wf2 = (const float*)d_in[20];
  const float* bf2 = (const float*)d_in[21];
  float* out = (float*)d_out;

  const int n = in_sizes[2];      // 100000
  const int E = in_sizes[1] / 2;  // 1200000

  char* w = (char*)d_ws;
  auto alloc = [&](size_t bytes) {
    void* p = (void*)w;
    w += (bytes + 255) & ~(size_t)255;
    return p;
  };
  int* deg = (int*)alloc((size_t)(n + 4) * 4);           // +4 pad for int4
  int* ell = (int*)alloc((size_t)(n + 4) * ELLS * 4);    // +4 pad rows
  ushort* Ybf = (ushort*)alloc((size_t)(n + 1) * 64 * 2);  // +1 zero row
  ushort* Yrbf = (ushort*)alloc((size_t)n * 64 * 2);
  ushort* Tbf = (ushort*)alloc((size_t)n * 64 * 2);
  ushort* Whi1 = (ushort*)alloc(128 * 128 * 2);
  ushort* Wlo1 = (ushort*)alloc(128 * 128 * 2);
  ushort* Whi2 = (ushort*)alloc(128 * 64 * 2);
  ushort* Wlo2 = (ushort*)alloc(128 * 64 * 2);
  ushort* Whi3 = (ushort*)alloc(128 * 64 * 2);
  ushort* Wlo3 = (ushort*)alloc(128 * 64 * 2);
  float* stats = (float*)alloc(3 * 128 * 4);

  hipMemsetAsync(deg, 0, (size_t)(n + 4) * 4, stream);
  hipMemsetAsync(stats, 0, 3 * 128 * 4, stream);
  hipMemsetAsync(Ybf + (size_t)n * 64, 0, 128, stream);  // zero sentinel row

  const int cnt4 = (n + 4) * (ELLS / 4);
  ell_init<<<(cnt4 + 255) / 256, 256, 0, stream>>>((int4*)ell, n, cnt4);
  const int bps = 2048;
  ell_fill_sharded<<<16 * bps, 256, 0, stream>>>(ei, deg, ell, E, n, bps);
  prep_w<<<64, 256, 0, stream>>>(W1l, W1r, Whi1, Wlo1, 128);
  prep_w<<<32, 256, 0, stream>>>(W2l, W2r, Whi2, Wlo2, 64);
  prep_w<<<32, 256, 0, stream>>>(W3l, W3r, Whi3, Wlo3, 64);

  const int gTile = (n + 63) / 64;
  const int gGath = 2048;

  // ---- layer 1
  gemm_mfma<128, false, false><<<gTile, 256, 0, stream>>>(
      x, nullptr, nullptr, nullptr, Whi1, Wlo1, Ybf, Yrbf, n);
  gather_combine<<<gGath, 256, 0, stream>>>(Ybf, Yrbf, ell, deg, b1, Tbf,
                                            stats + 0, n);

  // ---- layer 2 (BN1 finalize + norm fused into GEMM A-loads)
  gemm_mfma<64, true, true><<<gTile, 256, 0, stream>>>(
      Tbf, stats + 0, g1, be1, Whi2, Wlo2, Ybf, Yrbf, n);
  gather_combine<<<gGath, 256, 0, stream>>>(Ybf, Yrbf, ell, deg, b2, Tbf,
                                            stats + 128, n);

  // ---- layer 3
  gemm_mfma<64, true, true><<<gTile, 256, 0, stream>>>(
      Tbf, stats + 128, g2, be2, Whi3, Wlo3, Ybf, Yrbf, n);
  gather_combine<<<gGath, 256, 0, stream>>>(Ybf, Yrbf, ell, deg, b3, Tbf,
                                            stats + 256, n);

  // ---- fusion MLP (BN3 finalize + norm fused in)
  fusion_fused<<<gTile, 256, 0, stream>>>(Tbf, stats + 256, g3, be3, xgb, Wf1,
                                          bf1, Wf2, bf2, out, n);
}